// Round 6
// baseline (47.132 us; speedup 1.0000x reference)
//
#include <hip/hip_runtime.h>
#include <math.h>

// Sizes fixed by the reference.
#define BSZ  16
#define DIM  1024
#define DPB  16        // d-channels per block (64B global granule)
#define THREADS 512    // 8 waves; each half-wave (32 lanes) owns one (b,d) image
#define SSTRIDE 17     // LDS float-stride per s-cell: 17*31=527==15 (mod 32),
                       // gcd(15,32)=1 -> compute reads hit all 32 banks once
#define LDSF   17472   // covers max idx 17*1026+15 incl. prefetch overrun
#define LDSB   (LDSF * 4)   // 69888 B dynamic LDS -> 2 blocks/CU (139.8KB/160KB)

__device__ __forceinline__ float sigmoidf_(float v) {
    return __builtin_amdgcn_rcpf(1.0f + __expf(-v));
}

extern __shared__ float xs[];

// 2D SSM run as the recurrence directly on x (== causal conv with the impulse
// response == reference FFT path, by linearity/shift-invariance/causality):
//   v[i,j] = a2*h[i-1,j] + a1*v[i-1,j] + b2*x[i,j]
//   h[i,j] = a1*h[i,j-1] + a2*v[i,j-1] + b1*x[i,j]
//   y[i,j] = <h,C1*s> + <v,C2*s>;  out = silu(y + x*omega)
//
// Anti-diagonal wavefront (lane = row i, step ts, j = ts-i), neighbor state
// folded into v_fmac_f32_dpp wave_shr:1 (lane0 zeroed by bound_ctrl:0,
// half-wave row-0 zeroed via a1z/a2z coefficients).
//
// R6: tile-pipelined — each block runs TWO tiles (b, b+8; same d-group).
// Tile-1 global loads are issued into registers before tile-0 compute and
// stay in flight across it; tile-0 drain stores overlap tile-1 compute.
__global__ __launch_bounds__(THREADS, 1) void ssm2d_kernel(
    const float* __restrict__ x,
    const float* __restrict__ A1, const float* __restrict__ A2,
    const float* __restrict__ B1, const float* __restrict__ B2,
    const float* __restrict__ C1, const float* __restrict__ C2,
    const float* __restrict__ omega,
    float* __restrict__ out)
{
    const int bx = blockIdx.x;     // 0..511
    const int b0 = bx >> 6;        // 0..7  (second tile: b0+8)
    const int d0 = (bx & 63) * DPB;
    const int t  = threadIdx.x;

    // ---- per-lane channel & coefficients (same d for both tiles) ----
    const int lane = t & 63;
    const int wv   = t >> 6;               // wave 0..7
    const int dd   = 2 * wv + (lane >> 5); // image (d-index) 0..15
    const int i    = lane & 31;            // row owned by this lane
    const int d    = d0 + dd;

    const float2 fA1 = *reinterpret_cast<const float2*>(A1 + 2 * d);
    const float2 fA2 = *reinterpret_cast<const float2*>(A2 + 2 * d);
    const float2 fB1 = *reinterpret_cast<const float2*>(B1 + 2 * d);
    const float2 fB2 = *reinterpret_cast<const float2*>(B2 + 2 * d);
    const float2 fC1 = *reinterpret_cast<const float2*>(C1 + 2 * d);
    const float2 fC2 = *reinterpret_cast<const float2*>(C2 + 2 * d);
    const float  om  = omega[d];

    const float a1c0 = sigmoidf_(fA1.x) * 0.5f, a1c1 = sigmoidf_(fA1.y) * 0.5f;
    const float a2c0 = sigmoidf_(fA2.x) * 0.5f, a2c1 = sigmoidf_(fA2.y) * 0.5f;
    const float b1c0 = sigmoidf_(fB1.x) * 0.5f, b1c1 = sigmoidf_(fB1.y) * 0.5f;
    const float b2c0 = sigmoidf_(fB2.x) * 0.5f, b2c1 = sigmoidf_(fB2.y) * 0.5f;
    const float sc   = 0.70710678118654752f;
    const float c1s0 = fC1.x * sc, c1s1 = fC1.y * sc;
    const float c2s0 = fC2.x * sc, c2s1 = fC2.y * sc;
    const float a1z0 = (i == 0) ? 0.f : a1c0, a1z1 = (i == 0) ? 0.f : a1c1;
    const float a2z0 = (i == 0) ? 0.f : a2c0, a2z1 = (i == 0) ? 0.f : a2c1;

    // ---- staging/drain address components ----
    // g = t + 512k -> s = (t>>2)+128k, q = t&3
    const int sbase_f = (t >> 2) * (BSZ * DIM) + (t & 3) * 4 + d0;
    const int lds_t   = SSTRIDE * (t >> 2) + (t & 3) * 4;

    float4 L[8];

#define LOADT(B) {                                                           \
        const float* gp = x + (size_t)sbase_f + (size_t)(B) * DIM;           \
        _Pragma("unroll") for (int k = 0; k < 8; ++k)                        \
            L[k] = *reinterpret_cast<const float4*>(                         \
                gp + (size_t)k * (128 * BSZ * DIM)); }

#define WRITELDS() {                                                         \
        _Pragma("unroll") for (int k = 0; k < 8; ++k) {                      \
            float* p = xs + lds_t + k * (128 * SSTRIDE);                     \
            p[0]=L[k].x; p[1]=L[k].y; p[2]=L[k].z; p[3]=L[k].w; } }

#define DRAINT(B) {                                                          \
        float* op = out + (size_t)sbase_f + (size_t)(B) * DIM;               \
        _Pragma("unroll") for (int k = 0; k < 8; ++k) {                      \
            const float* p = xs + lds_t + k * (128 * SSTRIDE);               \
            float4 v; v.x=p[0]; v.y=p[1]; v.z=p[2]; v.w=p[3];                \
            *reinterpret_cast<float4*>(op + (size_t)k * (128 * BSZ * DIM)) = v; } }

    // compute read/write base: addr(ts) = 527*i + dd + 17*ts (linear in ts)
    float* rp = xs + 527 * i + dd;

#define SSTEP(TS, XQ) do {                                                   \
        const bool  valid = ((unsigned)((TS) - i) < 32u);                    \
        const float xv    = valid ? (XQ) : 0.f;                              \
        const float t10 = b1c0 * xv, t11 = b1c1 * xv;                        \
        const float hn0 = fmaf(a1c0, h0, fmaf(a2c0, v0, t10));               \
        const float hn1 = fmaf(a1c1, h1, fmaf(a2c1, v1, t11));               \
        float vn0 = b2c0 * xv, vn1 = b2c1 * xv;                              \
        asm("s_nop 1\n\t"                                                    \
            "v_fmac_f32_dpp %0, %2, %6 wave_shr:1 row_mask:0xf bank_mask:0xf bound_ctrl:0\n\t" \
            "v_fmac_f32_dpp %1, %3, %7 wave_shr:1 row_mask:0xf bank_mask:0xf bound_ctrl:0\n\t" \
            "v_fmac_f32_dpp %0, %4, %8 wave_shr:1 row_mask:0xf bank_mask:0xf bound_ctrl:0\n\t" \
            "v_fmac_f32_dpp %1, %5, %9 wave_shr:1 row_mask:0xf bank_mask:0xf bound_ctrl:0"     \
            : "+v"(vn0), "+v"(vn1)                                           \
            : "v"(h0), "v"(h1), "v"(v0), "v"(v1),                            \
              "v"(a2z0), "v"(a2z1), "v"(a1z0), "v"(a1z1));                   \
        float y = hn0 * c1s0;                                                \
        y = fmaf(hn1, c1s1, y);                                              \
        y = fmaf(vn0, c2s0, y);                                              \
        y = fmaf(vn1, c2s1, y);                                              \
        const float z = fmaf(xv, om, y);                                     \
        const float o = z * sigmoidf_(z);                                    \
        if (valid) rp[SSTRIDE * (TS)] = o;                                   \
        h0 = hn0; h1 = hn1; v0 = vn0; v1 = vn1;                              \
    } while (0)

#define COMPUTE() {                                                          \
        float h0 = 0.f, h1 = 0.f, v0 = 0.f, v1 = 0.f;                        \
        float xq0 = rp[0 * SSTRIDE];                                         \
        float xq1 = rp[1 * SSTRIDE];                                         \
        float xq2 = rp[2 * SSTRIDE];                                         \
        _Pragma("unroll") for (int ts = 0; ts < 63; ts += 3) {               \
            SSTEP(ts + 0, xq0); xq0 = rp[SSTRIDE * (ts + 3)];                \
            SSTEP(ts + 1, xq1); xq1 = rp[SSTRIDE * (ts + 4)];                \
            SSTEP(ts + 2, xq2); xq2 = rp[SSTRIDE * (ts + 5)];                \
        } }

    // ---- pipeline: stage0 | compute0 (loads1 in flight) | drain0 |
    //                 write1 | compute1 | drain1 ----
    LOADT(b0);
    WRITELDS();
    LOADT(b0 + 8);          // tile-1 loads in flight across compute0
    __syncthreads();
    COMPUTE();
    __syncthreads();
    DRAINT(b0);             // stores fire-and-forget, overlap what follows
    __syncthreads();        // drain reads done before LDS overwrite
    WRITELDS();             // implicit vmcnt wait: tile-1 data arrived long ago
    __syncthreads();
    COMPUTE();
    __syncthreads();
    DRAINT(b0 + 8);

#undef SSTEP
#undef COMPUTE
#undef LOADT
#undef WRITELDS
#undef DRAINT
}

extern "C" void kernel_launch(void* const* d_in, const int* in_sizes, int n_in,
                              void* d_out, int out_size, void* d_ws, size_t ws_size,
                              hipStream_t stream) {
    const float* x     = (const float*)d_in[0];
    const float* A1    = (const float*)d_in[1];
    const float* A2    = (const float*)d_in[2];
    const float* B1    = (const float*)d_in[3];
    const float* B2    = (const float*)d_in[4];
    const float* C1    = (const float*)d_in[5];
    const float* C2    = (const float*)d_in[6];
    const float* omega = (const float*)d_in[7];
    float* out = (float*)d_out;

    (void)hipFuncSetAttribute(reinterpret_cast<const void*>(ssm2d_kernel),
                              hipFuncAttributeMaxDynamicSharedMemorySize, LDSB);

    dim3 grid(512);                 // 64 d-groups x 8 b-pairs; 2 tiles/block
    dim3 block(THREADS);
    hipLaunchKernelGGL(ssm2d_kernel, grid, block, LDSB, stream,
                       x, A1, A2, B1, B2, C1, C2, omega, out);
}

// Round 7
// 40.579 us; speedup vs baseline: 1.1615x; 1.1615x over previous
//
#include <hip/hip_runtime.h>
#include <math.h>

// Sizes fixed by the reference.
#define BSZ  16
#define DIM  1024
#define DPB  16        // d-channels per tile (64B global granule)
#define THREADS 1024   // waves 0-7 compute, waves 8-15 memory
#define TPB  4         // tiles per block (b = 4*bq + k), grid = 256 = 1 block/CU
#define SSTRIDE 17     // LDS float-stride per s-cell: 17*31=527==15 (mod 32)
#define BUFF 17472     // floats per buffer (covers 17*1023+15 + prefetch overrun)
#define LDSB (2 * BUFF * 4)   // 139776 B -> exactly 1 block/CU (160KB limit)

__device__ __forceinline__ float sigmoidf_(float v) {
    return __builtin_amdgcn_rcpf(1.0f + __expf(-v));
}

extern __shared__ float xs[];

// 2D SSM run as the recurrence directly on x (== causal conv with the impulse
// response == reference FFT path, by linearity/shift-invariance/causality):
//   v[i,j] = a2*h[i-1,j] + a1*v[i-1,j] + b2*x[i,j]
//   h[i,j] = a1*h[i,j-1] + a2*v[i,j-1] + b1*x[i,j]
//   y[i,j] = <h,C1*s> + <v,C2*s>;  out = silu(y + x*omega)
//
// Anti-diagonal wavefront compute (lane = row i, step ts, j = ts-i), neighbor
// state folded into v_fmac_f32_dpp wave_shr:1 (lane0 zeroed by bound_ctrl:0,
// half-wave row-0 zeroed via a1z/a2z coefficients).
//
// R7: producer/consumer wave specialization. Waves 0-7 only compute; waves
// 8-15 only move memory (issue next-tile loads early -> drain prev-tile
// output -> LDS-write staged tile). Drain-read and stage-write touch the
// SAME cells from the SAME thread, so one barrier per tile suffices.
// Memory issue is continuous across the kernel -> compute hides under it.
__global__ __launch_bounds__(THREADS, 1) void ssm2d_kernel(
    const float* __restrict__ x,
    const float* __restrict__ A1, const float* __restrict__ A2,
    const float* __restrict__ B1, const float* __restrict__ B2,
    const float* __restrict__ C1, const float* __restrict__ C2,
    const float* __restrict__ omega,
    float* __restrict__ out)
{
    const int bx = blockIdx.x;     // 0..255
    const int bq = bx >> 6;        // 0..3  -> tiles b = 4*bq + k
    const int d0 = (bx & 63) * DPB;
    const int t  = threadIdx.x;

    const int lane = t & 63;
    const int wv   = t >> 6;               // wave 0..15
    const int i    = lane & 31;            // compute: row owned by this lane

    // ---- compute-wave coefficients (waves 0-7 only) ----
    float a1c0, a1c1, a2c0, a2c1, b1c0, b1c1, b2c0, b2c1;
    float c1s0, c1s1, c2s0, c2s1, om;
    float a1z0, a1z1, a2z0, a2z1;
    int dd = 0;
    if (t < 512) {
        dd = 2 * wv + (lane >> 5);         // image (d-index) 0..15
        const int d = d0 + dd;
        const float2 fA1 = *reinterpret_cast<const float2*>(A1 + 2 * d);
        const float2 fA2 = *reinterpret_cast<const float2*>(A2 + 2 * d);
        const float2 fB1 = *reinterpret_cast<const float2*>(B1 + 2 * d);
        const float2 fB2 = *reinterpret_cast<const float2*>(B2 + 2 * d);
        const float2 fC1 = *reinterpret_cast<const float2*>(C1 + 2 * d);
        const float2 fC2 = *reinterpret_cast<const float2*>(C2 + 2 * d);
        om   = omega[d];
        a1c0 = sigmoidf_(fA1.x) * 0.5f;  a1c1 = sigmoidf_(fA1.y) * 0.5f;
        a2c0 = sigmoidf_(fA2.x) * 0.5f;  a2c1 = sigmoidf_(fA2.y) * 0.5f;
        b1c0 = sigmoidf_(fB1.x) * 0.5f;  b1c1 = sigmoidf_(fB1.y) * 0.5f;
        b2c0 = sigmoidf_(fB2.x) * 0.5f;  b2c1 = sigmoidf_(fB2.y) * 0.5f;
        const float sc = 0.70710678118654752f;
        c1s0 = fC1.x * sc;  c1s1 = fC1.y * sc;
        c2s0 = fC2.x * sc;  c2s1 = fC2.y * sc;
        a1z0 = (i == 0) ? 0.f : a1c0;  a1z1 = (i == 0) ? 0.f : a1c1;
        a2z0 = (i == 0) ? 0.f : a2c0;  a2z1 = (i == 0) ? 0.f : a2c1;
    }

    // ---- prologue: all 1024 threads stage tile 0 into buf0 ----
    {
        const int   srow  = t >> 2;            // 0..255
        const int   qq    = (t & 3) * 4;
        const float* gp = x + (size_t)srow * (BSZ * DIM)
                            + (size_t)(4 * bq) * DIM + d0 + qq;
        float4 P[4];
        #pragma unroll
        for (int k2 = 0; k2 < 4; ++k2)
            P[k2] = *reinterpret_cast<const float4*>(
                gp + (size_t)k2 * (256 * BSZ * DIM));
        #pragma unroll
        for (int k2 = 0; k2 < 4; ++k2) {
            float* p = xs + SSTRIDE * (srow + 256 * k2) + qq;
            p[0] = P[k2].x; p[1] = P[k2].y; p[2] = P[k2].z; p[3] = P[k2].w;
        }
    }
    __syncthreads();

#define SSTEP(TS, XQ) do {                                                   \
        const bool  valid = ((unsigned)((TS) - i) < 32u);                    \
        const float xv    = valid ? (XQ) : 0.f;                              \
        const float t10 = b1c0 * xv, t11 = b1c1 * xv;                        \
        const float hn0 = fmaf(a1c0, h0, fmaf(a2c0, v0, t10));               \
        const float hn1 = fmaf(a1c1, h1, fmaf(a2c1, v1, t11));               \
        float vn0 = b2c0 * xv, vn1 = b2c1 * xv;                              \
        asm("s_nop 1\n\t"                                                    \
            "v_fmac_f32_dpp %0, %2, %6 wave_shr:1 row_mask:0xf bank_mask:0xf bound_ctrl:0\n\t" \
            "v_fmac_f32_dpp %1, %3, %7 wave_shr:1 row_mask:0xf bank_mask:0xf bound_ctrl:0\n\t" \
            "v_fmac_f32_dpp %0, %4, %8 wave_shr:1 row_mask:0xf bank_mask:0xf bound_ctrl:0\n\t" \
            "v_fmac_f32_dpp %1, %5, %9 wave_shr:1 row_mask:0xf bank_mask:0xf bound_ctrl:0"     \
            : "+v"(vn0), "+v"(vn1)                                           \
            : "v"(h0), "v"(h1), "v"(v0), "v"(v1),                            \
              "v"(a2z0), "v"(a2z1), "v"(a1z0), "v"(a1z1));                   \
        float y = hn0 * c1s0;                                                \
        y = fmaf(hn1, c1s1, y);                                              \
        y = fmaf(vn0, c2s0, y);                                              \
        y = fmaf(vn1, c2s1, y);                                              \
        const float z = fmaf(xv, om, y);                                     \
        const float o = z * sigmoidf_(z);                                    \
        if (valid) rp[SSTRIDE * (TS)] = o;                                   \
        h0 = hn0; h1 = hn1; v0 = vn0; v1 = vn1;                              \
    } while (0)

    // ---- main loop: one barrier per tile ----
    #pragma unroll 1
    for (int k = 0; k < TPB; ++k) {
        float* bufC = xs + (k & 1) * BUFF;          // tile k (input->output)
        float* bufO = xs + ((k + 1) & 1) * BUFF;    // tile k-1 out / k+1 in

        if (t < 512) {
            // -------- compute waves --------
            float* rp = bufC + 527 * i + dd;
            float h0 = 0.f, h1 = 0.f, v0 = 0.f, v1 = 0.f;
            float xq0 = rp[0 * SSTRIDE];
            float xq1 = rp[1 * SSTRIDE];
            float xq2 = rp[2 * SSTRIDE];
            #pragma unroll
            for (int ts = 0; ts < 63; ts += 3) {
                SSTEP(ts + 0, xq0); xq0 = rp[SSTRIDE * (ts + 3)];
                SSTEP(ts + 1, xq1); xq1 = rp[SSTRIDE * (ts + 4)];
                SSTEP(ts + 2, xq2); xq2 = rp[SSTRIDE * (ts + 5)];
            }
        } else {
            // -------- memory waves --------
            const int   m    = t - 512;            // 0..511
            const int   srow = m >> 2;             // 0..127
            const int   qq   = (m & 3) * 4;
            const size_t gb  = (size_t)srow * (BSZ * DIM) + d0 + qq;

            float4 L[8];
            if (k < TPB - 1) {                     // issue next-tile loads early
                const float* gp = x + gb + (size_t)(4 * bq + k + 1) * DIM;
                #pragma unroll
                for (int k2 = 0; k2 < 8; ++k2)
                    L[k2] = *reinterpret_cast<const float4*>(
                        gp + (size_t)k2 * (128 * BSZ * DIM));
            }
            if (k > 0) {                           // drain tile k-1 output
                float* op = out + gb + (size_t)(4 * bq + k - 1) * DIM;
                #pragma unroll
                for (int k2 = 0; k2 < 8; ++k2) {
                    const float* p = bufO + SSTRIDE * (srow + 128 * k2) + qq;
                    float4 v; v.x = p[0]; v.y = p[1]; v.z = p[2]; v.w = p[3];
                    *reinterpret_cast<float4*>(
                        op + (size_t)k2 * (128 * BSZ * DIM)) = v;
                }
            }
            if (k < TPB - 1) {                     // stage tile k+1 (same cells)
                #pragma unroll
                for (int k2 = 0; k2 < 8; ++k2) {
                    float* p = bufO + SSTRIDE * (srow + 128 * k2) + qq;
                    p[0] = L[k2].x; p[1] = L[k2].y;
                    p[2] = L[k2].z; p[3] = L[k2].w;
                }
            }
        }
        __syncthreads();
    }
#undef SSTEP

    // ---- epilogue: all 1024 threads drain tile TPB-1 from buf[(TPB-1)&1] ----
    {
        const int   srow = t >> 2;                 // 0..255
        const int   qq   = (t & 3) * 4;
        const float* bufE = xs + ((TPB - 1) & 1) * BUFF;
        float* op = out + (size_t)srow * (BSZ * DIM)
                        + (size_t)(4 * bq + TPB - 1) * DIM + d0 + qq;
        #pragma unroll
        for (int k2 = 0; k2 < 4; ++k2) {
            const float* p = bufE + SSTRIDE * (srow + 256 * k2) + qq;
            float4 v; v.x = p[0]; v.y = p[1]; v.z = p[2]; v.w = p[3];
            *reinterpret_cast<float4*>(op + (size_t)k2 * (256 * BSZ * DIM)) = v;
        }
    }
}

extern "C" void kernel_launch(void* const* d_in, const int* in_sizes, int n_in,
                              void* d_out, int out_size, void* d_ws, size_t ws_size,
                              hipStream_t stream) {
    const float* x     = (const float*)d_in[0];
    const float* A1    = (const float*)d_in[1];
    const float* A2    = (const float*)d_in[2];
    const float* B1    = (const float*)d_in[3];
    const float* B2    = (const float*)d_in[4];
    const float* C1    = (const float*)d_in[5];
    const float* C2    = (const float*)d_in[6];
    const float* omega = (const float*)d_in[7];
    float* out = (float*)d_out;

    (void)hipFuncSetAttribute(reinterpret_cast<const void*>(ssm2d_kernel),
                              hipFuncAttributeMaxDynamicSharedMemorySize, LDSB);

    dim3 grid(256);                 // 64 d-groups x 4 b-quads; 4 tiles/block
    dim3 block(THREADS);
    hipLaunchKernelGGL(ssm2d_kernel, grid, block, LDSB, stream,
                       x, A1, A2, B1, B2, C1, C2, omega, out);
}